// Round 13
// baseline (171.653 us; speedup 1.0000x reference)
//
#include <hip/hip_runtime.h>
#include <stdint.h>
#include <stddef.h>

#define BB 4
#define CC 128
#define HWN 4096
#define LOG2E 1.4426950408889634f

typedef __bf16 bf16x2 __attribute__((ext_vector_type(2)));
typedef __bf16 bf16x8 __attribute__((ext_vector_type(8)));
typedef float f32x16 __attribute__((ext_vector_type(16)));

__device__ __forceinline__ void g2l16(void* lds_ptr, const void* gptr) {
  __builtin_amdgcn_global_load_lds(
      (const __attribute__((address_space(1))) uint32_t*)gptr,
      (__attribute__((address_space(3))) uint32_t*)lds_ptr,
      16, 0, 0);
}

// k-slot permutation of mfma_32x32x16 within 16-elem groups:
// x = 4h + a + 8b (a 0..3, b 0..1, h = lane-half) -> 8h + 4b + a
__device__ __forceinline__ int p16(int x) {
  return ((x & 4) << 1) | ((x & 8) >> 1) | (x & 3);
}

// ---------------- W2 = out_w @ g1w, b2 = out_w @ g1b (f32, tiny) ----------------
__global__ __launch_bounds__(128) void w2prep_kernel(
    const float* __restrict__ outw, const float* __restrict__ g1w,
    const float* __restrict__ g1b, float* __restrict__ W2, float* __restrict__ b2) {
  int o = blockIdx.x;
  int c = threadIdx.x;
  float acc = 0.f;
#pragma unroll 8
  for (int k = 0; k < CC; ++k)
    acc = fmaf(outw[o * CC + k], g1w[k * CC + c], acc);
  W2[o * CC + c] = acc;
  if (c == 0) {
    float s = 0.f;
#pragma unroll 8
    for (int k = 0; k < CC; ++k) s = fmaf(outw[o * CC + k], g1b[k], s);
    b2[o] = s;
  }
}

// ---------------- per-(b,c) mean/rstd over HW (unbiased var, +eps) -------------
__global__ __launch_bounds__(256) void moments_kernel(
    const float* __restrict__ content, const float* __restrict__ guidance,
    float2* __restrict__ mom) {
  int row = blockIdx.x;  // b*C + c
  const float* x = (blockIdx.y ? guidance : content) + (size_t)row * HWN;
  int tid = threadIdx.x;
  float s1 = 0.f, s2 = 0.f;
#pragma unroll
  for (int i = 0; i < 16; ++i) {
    float v = x[tid + i * 256];
    s1 += v; s2 += v * v;
  }
#pragma unroll
  for (int off = 32; off > 0; off >>= 1) {
    s1 += __shfl_down(s1, off);
    s2 += __shfl_down(s2, off);
  }
  __shared__ float r1[4], r2[4];
  int wid = tid >> 6;
  if ((tid & 63) == 0) { r1[wid] = s1; r2[wid] = s2; }
  __syncthreads();
  if (tid == 0) {
    float t1 = r1[0] + r1[1] + r1[2] + r1[3];
    float t2 = r2[0] + r2[1] + r2[2] + r2[3];
    float mean = t1 * (1.f / HWN);
    float var = (t2 - (float)HWN * mean * mean) * (1.f / (HWN - 1));
    mom[blockIdx.y * (BB * CC) + row] = make_float2(mean, rsqrtf(var + 1e-5f));
  }
}

// ---------------- 1x1 conv with LDS x-staging: 64 p per block ------------------
// zc: mode = zc>>1, ohalf = zc&1 (64 outputs/block, 16 per wave, 1 p per thread)
// mode 0: KT = bf16(g1w@mvn(content)+g1b)            -> [p][p16 ch]
// mode 1: QT = bf16((fw@mvn(guidance)+fb)*LOG2E)     -> [p][p16 ch]
// mode 2: V2 = bf16(hw@guidance+hb)                  -> tile-blocked [b][p/32][c][ws]
// mode 3: T  = W2@mvn(content)+b2, f32               -> [c][p]
__global__ __launch_bounds__(256, 4) void conv_kernel(
    const float* __restrict__ content, const float* __restrict__ guidance,
    const float* __restrict__ g1w, const float* __restrict__ g1b,
    const float* __restrict__ fw, const float* __restrict__ fb,
    const float* __restrict__ hwt, const float* __restrict__ hb,
    const float* __restrict__ W2, const float* __restrict__ b2,
    const float2* __restrict__ mom,
    float* __restrict__ Tf,
    __bf16* __restrict__ QTb, __bf16* __restrict__ KTb, __bf16* __restrict__ Vb) {
  __shared__ float Xl[128][64];  // 32 KB staged (normalized) input tile
  int zc = blockIdx.z;
  int mode = zc >> 1;
  int ohalf = zc & 1;
  int b = blockIdx.y;
  int lane = threadIdx.x & 63;
  int wid = threadIdx.x >> 6;
  int swid = __builtin_amdgcn_readfirstlane(wid);
  int p0q = blockIdx.x * 64;
  const float* x; const float* w; const float* bias; const float2* mm;
  if (mode == 0)      { x = content;  w = g1w; bias = g1b; mm = mom; }
  else if (mode == 1) { x = guidance; w = fw;  bias = fb;  mm = mom + BB * CC; }
  else if (mode == 2) { x = guidance; w = hwt; bias = hb;  mm = nullptr; }
  else                { x = content;  w = W2;  bias = b2;  mm = mom; }
  const float* xb = x + (size_t)b * CC * HWN;
  const float2* mb = mm ? mm + b * CC : nullptr;

  // stage: 8 float4 per thread, coalesced; mvn applied at stage time
#pragma unroll
  for (int it = 0; it < 8; ++it) {
    int idx = it * 256 + threadIdx.x;  // 2048 float4 = 128c x 64p
    int c = idx >> 4;
    int p4 = (idx & 15) * 4;
    float4 v = *(const float4*)(xb + (size_t)c * HWN + p0q + p4);
    if (mb) {
      float2 ms = mb[c];
      v.x = (v.x - ms.x) * ms.y; v.y = (v.y - ms.x) * ms.y;
      v.z = (v.z - ms.x) * ms.y; v.w = (v.w - ms.x) * ms.y;
    }
    *(float4*)&Xl[c][p4] = v;
  }
  __syncthreads();

  int p = p0q + lane;
  int obase = ohalf * 64 + wid * 16;
  const float* wbase = w + (size_t)(ohalf * 64 + swid * 16) * CC;  // scalar base
  float acc[16];
#pragma unroll
  for (int k = 0; k < 16; ++k) acc[k] = bias[obase + k];
#pragma unroll 2
  for (int c0 = 0; c0 < CC; c0 += 4) {
    float x0 = Xl[c0][lane], x1 = Xl[c0 + 1][lane];
    float x2 = Xl[c0 + 2][lane], x3 = Xl[c0 + 3][lane];
#pragma unroll
    for (int k = 0; k < 16; ++k) {
      const float4 wv = *(const float4*)(wbase + (size_t)k * CC + c0);
      acc[k] = fmaf(wv.x, x0, fmaf(wv.y, x1, fmaf(wv.z, x2, fmaf(wv.w, x3, acc[k]))));
    }
  }
  if (mode <= 1) {
    __bf16* T = (mode == 0) ? KTb : QTb;
    float scale = (mode == 1) ? LOG2E : 1.f;
    char* rowp = (char*)(T + ((size_t)b * HWN + p) * CC);
#pragma unroll
    for (int kk = 0; kk < 8; ++kk) {
      int o0 = obase + 2 * kk;
      int pp = (o0 & ~15) | p16(o0 & 15);  // even o0 -> pp, pp+1 adjacent
      bf16x2 pr = {(__bf16)(acc[2 * kk] * scale), (__bf16)(acc[2 * kk + 1] * scale)};
      *(bf16x2*)(rowp + pp * 2) = pr;
    }
  } else if (mode == 2) {
    int w_ = p & 31;
    int ws = (w_ & 16) | p16(w_ & 15);
    __bf16* tbase = Vb + ((size_t)(b * (HWN / 32) + (p >> 5)) * CC) * 32 + ws;
#pragma unroll
    for (int k = 0; k < 16; ++k)
      tbase[(size_t)(obase + k) * 32] = (__bf16)acc[k];
  } else {
#pragma unroll
    for (int k = 0; k < 16; ++k)
      Tf[((size_t)b * CC + obase + k) * HWN + p] = acc[k];
  }
}

// ---------------- flash attention: G2_pre[c,n] = sum_m V[c,m]*softmax_m(S[n,m]) --
// 1024 threads = 16 waves = 4 m-groups x 2 n-waves x 2 c-halves -> 4 waves/SIMD.
// Shared staging per m-group (K 8KB + V 8KB, double-buffered), Q resident in LDS,
// c-half split keeps per-wave regs <= ~123 (Of 32). One __syncthreads per iter
// (stage issued early -> full compute-phase lead). 32x32 MFMA lane-local softmax.
__global__ __launch_bounds__(1024, 4) void attn_kernel(
    const __bf16* __restrict__ QTb, const __bf16* __restrict__ KTb,
    const __bf16* __restrict__ Vb, float* __restrict__ G2p) {
  __shared__ __align__(16) char lds[147456];  // Q 16K | K 4grp x 2buf x 8K | V same
  int fid = blockIdx.x;                        // 256 blocks
  int swz = (fid & 7) * 32 + (fid >> 3);       // XCD swizzle
  int b = swz >> 6;
  int ntile = swz & 63;                        // 64 n-tiles of 64
  int tid = threadIdx.x;
  int lane = tid & 63;
  int wid = tid >> 6;        // 0..15
  int grp = wid >> 2;        // m-group 0..3
  int sub = wid & 3;         // 0..3 within group
  int nw = sub >> 1;         // n-wave (n 32-strip)
  int ch = sub & 1;          // c-half (64 channels)
  int l31 = lane & 31;
  int h = lane >> 5;
  int nb = ntile * 64;
  int qrow = nw * 32 + l31;

  char* Qlds  = lds;                                   // [64 rows][256B]
  char* kbase = lds + 16384 + (size_t)grp * 16384;     // 2 x 8KB
  char* vbase = lds + 81920 + (size_t)grp * 16384;     // 2 x 8KB

  const char* ktB = (const char*)(KTb + (size_t)b * HWN * CC);   // [m][p16 ch] 256B rows
  const char* qtB = (const char*)(QTb + ((size_t)b * HWN + nb) * CC);
  const char* vtB = (const char*)Vb + (size_t)(b * (HWN / 32) + grp * 32) * 8192;

  // stage tile i (m = grp*1024 + i*32) into buf (i&1); 4 waves x 4 ops, shared
  auto stage = [&](int i) {
    int m0 = grp * 1024 + i * 32;
    char* kb = kbase + (size_t)(i & 1) * 8192;
    char* vb = vbase + (size_t)(i & 1) * 8192;
#pragma unroll
    for (int j = 0; j < 2; ++j) {
      int op = sub * 2 + j;
      int t = op * 64 + lane;
      int row = t >> 4, u = t & 15;                     // K [32 rows][256B]
      g2l16(kb + (size_t)op * 1024,
            ktB + (size_t)(m0 + row) * 256 + (u ^ (row & 15)) * 16);
    }
#pragma unroll
    for (int j = 0; j < 2; ++j) {
      int op = sub * 2 + j;
      int t = op * 64 + lane;
      int c = t >> 2, u = t & 3;                        // V [128 c][64B]
      g2l16(vb + (size_t)op * 1024,
            vtB + (size_t)i * 8192 + (size_t)c * 64 + (u ^ ((c >> 1) & 3)) * 16);
    }
  };

  f32x16 Of[2];  // c-half: c = ch*64 + q*32 + (r&3)+8(r>>2)+4h, n = nb+nw*32+l31
#pragma unroll
  for (int q = 0; q < 2; ++q)
#pragma unroll
    for (int r = 0; r < 16; ++r) Of[q][r] = 0.f;
  float mrun = -1e30f, lrun = 0.f;

  // Q stage (once) + first K/V tile
  {
    int row = tid >> 4, u = tid & 15;
    g2l16(Qlds + (size_t)(tid >> 6) * 1024,
          qtB + (size_t)row * 256 + (u ^ (row & 15)) * 16);
  }
  stage(0);
  __syncthreads();

#pragma unroll 1
  for (int i = 0; i < 32; ++i) {
    if (i < 31) stage(i + 1);  // early issue: lands under this iter's compute
    const char* kt = kbase + (size_t)(i & 1) * 8192;
    const char* vv = vbase + (size_t)(i & 1) * 8192;
    f32x16 sa, sb2;
#pragma unroll
    for (int r = 0; r < 16; ++r) { sa[r] = 0.f; sb2[r] = 0.f; }
#pragma unroll
    for (int j = 0; j < 8; j += 2) {  // 2 independent accum chains
      bf16x8 k0 = *(const bf16x8*)(kt + l31 * 256 + (((2 * j + h) ^ (l31 & 15)) << 4));
      bf16x8 q0 = *(const bf16x8*)(Qlds + qrow * 256 + (((2 * j + h) ^ (qrow & 15)) << 4));
      bf16x8 k1 = *(const bf16x8*)(kt + l31 * 256 + (((2 * j + 2 + h) ^ (l31 & 15)) << 4));
      bf16x8 q1 = *(const bf16x8*)(Qlds + qrow * 256 + (((2 * j + 2 + h) ^ (qrow & 15)) << 4));
      sa  = __builtin_amdgcn_mfma_f32_32x32x16_bf16(k0, q0, sa, 0, 0, 0);
      sb2 = __builtin_amdgcn_mfma_f32_32x32x16_bf16(k1, q1, sb2, 0, 0, 0);
    }
    bf16x8 vf[4];
#pragma unroll
    for (int q = 0; q < 2; ++q) {
      int cr = ch * 64 + q * 32 + l31;
      int d = (cr >> 1) & 3;
#pragma unroll
      for (int kk = 0; kk < 2; ++kk)
        vf[q * 2 + kk] = *(const bf16x8*)(vv + cr * 64 + (((2 * kk + h) ^ d) << 4));
    }
    f32x16 s = sa + sb2;
    // lane-local softmax (lane holds 16 of 32 m for its n; partner lane^32 rest)
    float tm = s[0];
#pragma unroll
    for (int r = 1; r < 16; ++r) tm = fmaxf(tm, s[r]);
    tm = fmaxf(tm, __shfl_xor(tm, 32));
    if (!__all(tm <= mrun + 8.f)) {  // defer-max (base-2: P <= 2^8)
      float mnew = fmaxf(mrun, tm);
      float alpha = exp2f(mrun - mnew);
      lrun *= alpha;
#pragma unroll
      for (int q = 0; q < 2; ++q) Of[q] *= alpha;
      mrun = mnew;
    }
    float pe[16];
#pragma unroll
    for (int r = 0; r < 16; ++r) pe[r] = exp2f(s[r] - mrun);
    float t0 = (pe[0] + pe[1]) + (pe[2] + pe[3]);
    float t1 = (pe[4] + pe[5]) + (pe[6] + pe[7]);
    float t2 = (pe[8] + pe[9]) + (pe[10] + pe[11]);
    float t3 = (pe[12] + pe[13]) + (pe[14] + pe[15]);
    float ps = (t0 + t1) + (t2 + t3);
    ps += __shfl_xor(ps, 32);
    lrun += ps;
    bf16x8 pf0, pf1;  // S-reg -> PV B-operand k-slot mapping is identity
#pragma unroll
    for (int j = 0; j < 8; ++j) { pf0[j] = (__bf16)pe[j]; pf1[j] = (__bf16)pe[8 + j]; }
#pragma unroll
    for (int q = 0; q < 2; ++q) {
      Of[q] = __builtin_amdgcn_mfma_f32_32x32x16_bf16(vf[q * 2],     pf0, Of[q], 0, 0, 0);
      Of[q] = __builtin_amdgcn_mfma_f32_32x32x16_bf16(vf[q * 2 + 1], pf1, Of[q], 0, 0, 0);
    }
    __syncthreads();  // drains stage(i+1); syncs buffer swap across the group
  }

  // 4-way m-merge per (nw, ch): grp 1..3 write partials, grp 0 combines
  float* xch = (float*)lds;
  if (grp) {
    float* rec = xch + ((size_t)((grp - 1) * 4 + sub) * 64 + lane) * 34;
#pragma unroll
    for (int q = 0; q < 2; ++q)
#pragma unroll
      for (int r = 0; r < 16; ++r) rec[q * 16 + r] = Of[q][r];
    rec[32] = mrun;
    rec[33] = lrun;
  }
  __syncthreads();
  if (grp == 0) {
    const float* r1 = xch + ((size_t)(0 * 4 + sub) * 64 + lane) * 34;
    const float* r2 = xch + ((size_t)(1 * 4 + sub) * 64 + lane) * 34;
    const float* r3 = xch + ((size_t)(2 * 4 + sub) * 64 + lane) * 34;
    float m1 = r1[32], m2 = r2[32], m3 = r3[32];
    float mm = fmaxf(fmaxf(mrun, m1), fmaxf(m2, m3));
    float a0 = exp2f(mrun - mm), a1 = exp2f(m1 - mm);
    float a2 = exp2f(m2 - mm), a3 = exp2f(m3 - mm);
    float inv = 1.f / (lrun * a0 + r1[33] * a1 + r2[33] * a2 + r3[33] * a3);
    float* outp = G2p + (size_t)b * CC * HWN + nb + nw * 32 + l31;
#pragma unroll
    for (int q = 0; q < 2; ++q)
#pragma unroll
      for (int r = 0; r < 16; ++r) {
        int c = ch * 64 + q * 32 + (r & 3) + 8 * (r >> 2) + 4 * h;
        float v = Of[q][r] * a0 + r1[q * 16 + r] * a1 + r2[q * 16 + r] * a2 + r3[q * 16 + r] * a3;
        outp[(size_t)c * HWN] = v * inv;
      }
  }
}

// ---------------- per-(b,c) row softmax stats of G2_pre over n ------------------
__global__ __launch_bounds__(256) void smstats_kernel(
    const float* __restrict__ G2p, float2* __restrict__ smst) {
  int row = blockIdx.x;
  const float* x = G2p + (size_t)row * HWN;
  int tid = threadIdx.x;
  float v[16];
  float mx = -1e30f;
#pragma unroll
  for (int i = 0; i < 16; ++i) { v[i] = x[tid + i * 256]; mx = fmaxf(mx, v[i]); }
#pragma unroll
  for (int off = 32; off > 0; off >>= 1) mx = fmaxf(mx, __shfl_xor(mx, off));
  __shared__ float rm[4], rs[4];
  int wid = tid >> 6;
  if ((tid & 63) == 0) rm[wid] = mx;
  __syncthreads();
  float bmax = fmaxf(fmaxf(rm[0], rm[1]), fmaxf(rm[2], rm[3]));
  float s = 0.f;
#pragma unroll
  for (int i = 0; i < 16; ++i) s += __expf(v[i] - bmax);
#pragma unroll
  for (int off = 32; off > 0; off >>= 1) s += __shfl_xor(s, off);
  if ((tid & 63) == 0) rs[wid] = s;
  __syncthreads();
  if (tid == 0) {
    float tot = rs[0] + rs[1] + rs[2] + rs[3];
    smst[row] = make_float2(bmax, 1.f / tot);
  }
}

// ---------------- gamma/beta = channel-weighted sums of softmaxed G2 ------------
__global__ __launch_bounds__(256) void gammabeta_kernel(
    const float* __restrict__ G2p, const float2* __restrict__ smst,
    const float* __restrict__ gw, const float* __restrict__ bw,
    float* __restrict__ gamma, float* __restrict__ beta) {
  int b = blockIdx.y;
  int lane = threadIdx.x & 63;
  int cg = threadIdx.x >> 6;
  int m = blockIdx.x * 64 + lane;
  const float* base = G2p + (size_t)b * CC * HWN + m;
  float ag = 0.f, ab = 0.f;
#pragma unroll 8
  for (int ci = 0; ci < 32; ++ci) {
    int c = cg * 32 + ci;
    float2 st = smst[b * CC + c];
    float val = __expf(base[(size_t)c * HWN] - st.x) * st.y;
    ag = fmaf(gw[c], val, ag);
    ab = fmaf(bw[c], val, ab);
  }
  __shared__ float sg[4][64], sb[4][64];
  sg[cg][lane] = ag;
  sb[cg][lane] = ab;
  __syncthreads();
  if (threadIdx.x < 64) {
    int t = threadIdx.x;
    gamma[b * HWN + blockIdx.x * 64 + t] = sg[0][t] + sg[1][t] + sg[2][t] + sg[3][t];
    beta[b * HWN + blockIdx.x * 64 + t]  = sb[0][t] + sb[1][t] + sb[2][t] + sb[3][t];
  }
}

// ---- out[b,o] = T[b,o]@Gam[b] + rowsum(out_w[o,:])*Beta[b] + out_b[o] ----------
__global__ __launch_bounds__(256) void final_kernel(
    const float* __restrict__ Tf, const float* __restrict__ gamma,
    const float* __restrict__ beta, const float* __restrict__ outw,
    const float* __restrict__ outb, float* __restrict__ out) {
  int o = blockIdx.x, b = blockIdx.y;
  int j = threadIdx.x & 63;
  int wid = __builtin_amdgcn_readfirstlane(threadIdx.x >> 6);
  const float* gb_ = gamma + (size_t)b * HWN;
  float gr[64];
#pragma unroll
  for (int k = 0; k < 64; ++k) gr[k] = gb_[k * 64 + j];
  float wb = 0.f;
#pragma unroll 16
  for (int c = 0; c < CC; ++c) wb += outw[o * CC + c];
  float ob = outb[o];
  const float* trow0 = Tf + ((size_t)b * CC + o) * HWN;
  const float* bbase = beta + (size_t)b * HWN;
  float* obase = out + ((size_t)b * CC + o) * HWN;
#pragma unroll 4
  for (int r = 0; r < 16; ++r) {
    int i = r * 4 + wid;
    const float* tr = trow0 + i * 64;
    float a0 = 0.f, a1 = 0.f, a2 = 0.f, a3 = 0.f;
#pragma unroll
    for (int k = 0; k < 64; k += 4) {
      a0 = fmaf(tr[k],     gr[k],     a0);
      a1 = fmaf(tr[k + 1], gr[k + 1], a1);
      a2 = fmaf(tr[k + 2], gr[k + 2], a2);
      a3 = fmaf(tr[k + 3], gr[k + 3], a3);
    }
    obase[i * 64 + j] = (a0 + a1) + (a2 + a3) + wb * bbase[i * 64 + j] + ob;
  }
}

extern "C" void kernel_launch(void* const* d_in, const int* in_sizes, int n_in,
                              void* d_out, int out_size, void* d_ws, size_t ws_size,
                              hipStream_t stream) {
  (void)in_sizes; (void)n_in; (void)out_size; (void)ws_size;
  const float* content  = (const float*)d_in[0];
  const float* guidance = (const float*)d_in[1];
  const float* g1w = (const float*)d_in[2];
  const float* g1b = (const float*)d_in[3];
  const float* fw  = (const float*)d_in[4];
  const float* fb  = (const float*)d_in[5];
  const float* hwt = (const float*)d_in[6];
  const float* hb  = (const float*)d_in[7];
  const float* gw  = (const float*)d_in[8];
  const float* bw  = (const float*)d_in[9];
  const float* outw = (const float*)d_in[10];
  const float* outb = (const float*)d_in[11];

  char* ws = (char*)d_ws;
  const size_t MB_ = 1u << 20;
  float*  Tf  = (float*)(ws + 0);            // 8 MB
  float*  G2p = (float*)(ws + 8 * MB_);      // 8 MB
  __bf16* QTb = (__bf16*)(ws + 16 * MB_);    // 4 MB
  __bf16* KTb = (__bf16*)(ws + 20 * MB_);    // 4 MB
  __bf16* Vb  = (__bf16*)(ws + 24 * MB_);    // 4 MB (tile-blocked V2)
  float2* mom  = (float2*)(ws + 28 * MB_);                  // 8 KB
  float2* smst = (float2*)(ws + 28 * MB_ + 8192);           // 4 KB
  float*  gamma = (float*)(ws + 28 * MB_ + 16384);          // 64 KB
  float*  beta  = (float*)(ws + 28 * MB_ + 16384 + 65536);  // 64 KB
  float*  W2 = (float*)(ws + 28 * MB_ + 16384 + 2 * 65536); // 64 KB
  float*  b2 = (float*)(ws + 28 * MB_ + 16384 + 3 * 65536); // 512 B

  w2prep_kernel<<<dim3(CC), 128, 0, stream>>>(outw, g1w, g1b, W2, b2);
  moments_kernel<<<dim3(BB * CC, 2), 256, 0, stream>>>(content, guidance, mom);
  conv_kernel<<<dim3(HWN / 64, BB, 8), 256, 0, stream>>>(
      content, guidance, g1w, g1b, fw, fb, hwt, hb, W2, b2, mom,
      Tf, QTb, KTb, Vb);
  attn_kernel<<<dim3(256), 1024, 0, stream>>>(QTb, KTb, Vb, G2p);
  smstats_kernel<<<dim3(BB * CC), 256, 0, stream>>>(G2p, smst);
  gammabeta_kernel<<<dim3(HWN / 64, BB), 256, 0, stream>>>(G2p, smst, gw, bw, gamma, beta);
  final_kernel<<<dim3(CC, BB), 256, 0, stream>>>(Tf, gamma, beta, outw, outb, (float*)d_out);
}

// Round 14
// 118.106 us; speedup vs baseline: 1.4534x; 1.4534x over previous
//
#include <hip/hip_runtime.h>
#include <stdint.h>
#include <stddef.h>

#define BB 4
#define CC 128
#define HWN 4096
#define LOG2E 1.4426950408889634f

typedef __bf16 bf16x2 __attribute__((ext_vector_type(2)));
typedef __bf16 bf16x8 __attribute__((ext_vector_type(8)));
typedef float f32x16 __attribute__((ext_vector_type(16)));

__device__ __forceinline__ void g2l16(void* lds_ptr, const void* gptr) {
  __builtin_amdgcn_global_load_lds(
      (const __attribute__((address_space(1))) uint32_t*)gptr,
      (__attribute__((address_space(3))) uint32_t*)lds_ptr,
      16, 0, 0);
}

// k-slot permutation of mfma_32x32x16 within 16-elem groups:
// x = 4h + a + 8b (a 0..3, b 0..1, h = lane-half) -> 8h + 4b + a
__device__ __forceinline__ int p16(int x) {
  return ((x & 4) << 1) | ((x & 8) >> 1) | (x & 3);
}

// ---------------- W2 = out_w @ g1w, b2 = out_w @ g1b (f32, tiny) ----------------
__global__ __launch_bounds__(128) void w2prep_kernel(
    const float* __restrict__ outw, const float* __restrict__ g1w,
    const float* __restrict__ g1b, float* __restrict__ W2, float* __restrict__ b2) {
  int o = blockIdx.x;
  int c = threadIdx.x;
  float acc = 0.f;
#pragma unroll 8
  for (int k = 0; k < CC; ++k)
    acc = fmaf(outw[o * CC + k], g1w[k * CC + c], acc);
  W2[o * CC + c] = acc;
  if (c == 0) {
    float s = 0.f;
#pragma unroll 8
    for (int k = 0; k < CC; ++k) s = fmaf(outw[o * CC + k], g1b[k], s);
    b2[o] = s;
  }
}

// ---------------- per-(b,c) mean/rstd over HW (unbiased var, +eps) -------------
__global__ __launch_bounds__(256) void moments_kernel(
    const float* __restrict__ content, const float* __restrict__ guidance,
    float2* __restrict__ mom) {
  int row = blockIdx.x;  // b*C + c
  const float* x = (blockIdx.y ? guidance : content) + (size_t)row * HWN;
  int tid = threadIdx.x;
  float s1 = 0.f, s2 = 0.f;
#pragma unroll
  for (int i = 0; i < 16; ++i) {
    float v = x[tid + i * 256];
    s1 += v; s2 += v * v;
  }
#pragma unroll
  for (int off = 32; off > 0; off >>= 1) {
    s1 += __shfl_down(s1, off);
    s2 += __shfl_down(s2, off);
  }
  __shared__ float r1[4], r2[4];
  int wid = tid >> 6;
  if ((tid & 63) == 0) { r1[wid] = s1; r2[wid] = s2; }
  __syncthreads();
  if (tid == 0) {
    float t1 = r1[0] + r1[1] + r1[2] + r1[3];
    float t2 = r2[0] + r2[1] + r2[2] + r2[3];
    float mean = t1 * (1.f / HWN);
    float var = (t2 - (float)HWN * mean * mean) * (1.f / (HWN - 1));
    mom[blockIdx.y * (BB * CC) + row] = make_float2(mean, rsqrtf(var + 1e-5f));
  }
}

// ------- weight cast/fold: bf16 [o][c p16] (plain rows; conv XORs at source) ----
// y 0: WK=g1w | 1: WQ=fw*LOG2E (+BqL=fb*LOG2E) | 2: WT=W2f | 3..6: WV[b]=hw*std,
// hb_b[b][o]=hb[o]+hw[o,:]@mean (mvn folded so V-path consumes normalized x too)
__global__ __launch_bounds__(128) void wcast_kernel(
    const float* __restrict__ g1w, const float* __restrict__ fw,
    const float* __restrict__ fb, const float* __restrict__ hwt,
    const float* __restrict__ hb, const float* __restrict__ W2f,
    const float2* __restrict__ mom,
    __bf16* __restrict__ WK, __bf16* __restrict__ WQ, __bf16* __restrict__ WT,
    __bf16* __restrict__ WV, float* __restrict__ BqL, float* __restrict__ hb_b) {
  int row = blockIdx.x;
  int y = blockIdx.y;
  int c = threadIdx.x;
  int cp = (c & ~15) | p16(c & 15);
  if (y == 0) {
    WK[row * CC + cp] = (__bf16)g1w[row * CC + c];
  } else if (y == 1) {
    WQ[row * CC + cp] = (__bf16)(fw[row * CC + c] * LOG2E);
    if (c == 0) BqL[row] = fb[row] * LOG2E;
  } else if (y == 2) {
    WT[row * CC + cp] = (__bf16)W2f[row * CC + c];
  } else {
    int b = y - 3;
    float2 ms = mom[BB * CC + b * CC + c];
    WV[((size_t)b * CC + row) * CC + cp] = (__bf16)(hwt[row * CC + c] / ms.y);
    __shared__ float red[128];
    red[c] = hwt[row * CC + c] * ms.x;
    __syncthreads();
#pragma unroll
    for (int off = 64; off > 0; off >>= 1) {
      if (c < off) red[c] += red[c + off];
      __syncthreads();
    }
    if (c == 0) hb_b[b * CC + row] = hb[row] + red[0];
  }
}

// ---------------- MFMA 1x1 conv: z = 0 KT, 1 T, 2 QT, 3 V -----------------------
// Block: 256 thr, one (z, b, 128-p tile). Stage x (f32->mvn->bf16, [p][c p16],
// XOR-swizzled) + w (g2l16, source-XOR); 32x32x16 MFMA over 8 k-steps; store in
// the existing KT/QT/V2/T layouts (attention unchanged).
__global__ __launch_bounds__(256) void convm_kernel(
    const float* __restrict__ content, const float* __restrict__ guidance,
    const float2* __restrict__ mom,
    const __bf16* __restrict__ WK, const __bf16* __restrict__ WQ,
    const __bf16* __restrict__ WT, const __bf16* __restrict__ WV,
    const float* __restrict__ g1b, const float* __restrict__ b2,
    const float* __restrict__ BqL, const float* __restrict__ hb_b,
    float* __restrict__ Tf, __bf16* __restrict__ QTb, __bf16* __restrict__ KTb,
    __bf16* __restrict__ Vb) {
  __shared__ __align__(16) char lds[65536];  // x 32KB @0, w 32KB @32768
  int z = blockIdx.z;
  int b = blockIdx.y;
  int p0 = blockIdx.x * 128;
  int tid = threadIdx.x;
  int lane = tid & 63, wid = tid >> 6;
  int l31 = lane & 31, h = lane >> 5;
  const float* x = (z < 2 ? content : guidance) + (size_t)b * CC * HWN;
  const float2* mb = mom + (z < 2 ? 0 : BB * CC) + b * CC;
  const __bf16* wsel = (z == 0) ? WK : (z == 1) ? WT : (z == 2) ? WQ
                       : WV + (size_t)b * CC * CC;
  const float* bias = (z == 0) ? g1b : (z == 1) ? b2 : (z == 2) ? BqL
                      : hb_b + b * CC;

  // stage w (32KB) via g2l16: 8 ops/thread, per-wave 1KB chunks, source-XOR
  {
    const char* wG = (const char*)wsel;
    char* wl = lds + 32768;
#pragma unroll
    for (int op = 0; op < 8; ++op) {
      int ck = op * 4 + wid;                 // 0..31 x 1KB
      int row = ck * 4 + (lane >> 4);
      int u = lane & 15;
      g2l16(wl + (size_t)ck * 1024,
            wG + (size_t)row * 256 + ((u ^ (row & 15)) << 4));
    }
  }
  // stage x: thread owns 2 p-rows x 32 c; mvn+cvt+swizzled transpose into LDS
  {
    char* xl = lds;
    int pl = (tid & 63) * 2;
    int c0 = (tid >> 6) * 32;
#pragma unroll 8
    for (int k = 0; k < 32; ++k) {
      int c = c0 + k;
      float2 ms = mb[c];
      float2 v = *(const float2*)(x + (size_t)c * HWN + p0 + pl);
      __bf16 e0 = (__bf16)((v.x - ms.x) * ms.y);
      __bf16 e1 = (__bf16)((v.y - ms.x) * ms.y);
      int cp = (c & ~15) | p16(c & 15);
      int cb = (cp * 2) & 15;
      *(__bf16*)(xl + pl * 256 + ((((cp >> 3) ^ (pl & 15)) << 4) | cb)) = e0;
      *(__bf16*)(xl + (pl + 1) * 256 + ((((cp >> 3) ^ ((pl + 1) & 15)) << 4) | cb)) = e1;
    }
  }
  __syncthreads();

  f32x16 Of[4];
#pragma unroll
  for (int q = 0; q < 4; ++q)
#pragma unroll
    for (int r = 0; r < 16; ++r) Of[q][r] = 0.f;
  const char* xl = lds;
  const char* wl = lds + 32768;
  int xrow = wid * 32 + l31;
#pragma unroll
  for (int j = 0; j < 8; ++j) {
    bf16x8 xf = *(const bf16x8*)(xl + xrow * 256 + (((2 * j + h) ^ (xrow & 15)) << 4));
#pragma unroll
    for (int q = 0; q < 4; ++q) {
      int wrow = q * 32 + l31;
      bf16x8 wf = *(const bf16x8*)(wl + wrow * 256 + (((2 * j + h) ^ (wrow & 15)) << 4));
      Of[q] = __builtin_amdgcn_mfma_f32_32x32x16_bf16(wf, xf, Of[q], 0, 0, 0);
    }
  }

  int p = p0 + wid * 32 + l31;
  if (z == 0 || z == 2) {           // KT/QT: [p][o p16] bf16, paired stores
    __bf16* T = (z == 0) ? KTb : QTb;
    char* rowp = (char*)(T + ((size_t)b * HWN + p) * CC);
#pragma unroll
    for (int q = 0; q < 4; ++q)
#pragma unroll
      for (int r = 0; r < 16; r += 2) {
        int o = q * 32 + (r & 3) + 8 * (r >> 2) + 4 * h;
        bf16x2 pr = {(__bf16)(Of[q][r] + bias[o]), (__bf16)(Of[q][r + 1] + bias[o + 1])};
        int pp = (o & ~15) | p16(o & 15);
        *(bf16x2*)(rowp + pp * 2) = pr;
      }
  } else if (z == 1) {              // T: f32 [c][p]
#pragma unroll
    for (int q = 0; q < 4; ++q)
#pragma unroll
      for (int r = 0; r < 16; ++r) {
        int o = q * 32 + (r & 3) + 8 * (r >> 2) + 4 * h;
        Tf[((size_t)b * CC + o) * HWN + p] = Of[q][r] + bias[o];
      }
  } else {                          // V2 tile-blocked: [b][p/32][c][ws]
    int ws_ = (l31 & 16) | p16(l31 & 15);
    __bf16* tbase = Vb + ((size_t)(b * (HWN / 32) + (p >> 5)) * CC) * 32 + ws_;
#pragma unroll
    for (int q = 0; q < 4; ++q)
#pragma unroll
      for (int r = 0; r < 16; ++r) {
        int o = q * 32 + (r & 3) + 8 * (r >> 2) + 4 * h;
        tbase[(size_t)o * 32] = (__bf16)(Of[q][r] + bias[o]);
      }
  }
}

// ---------------- flash attention (R12 structure, unchanged: best = 80us) -------
__global__ __launch_bounds__(512, 2) void attn_kernel(
    const __bf16* __restrict__ QTb, const __bf16* __restrict__ KTb,
    const __bf16* __restrict__ Vb, float* __restrict__ G2p) {
  __shared__ __align__(16) char lds[131072];
  int fid = blockIdx.x;
  int swz = (fid & 7) * 32 + (fid >> 3);
  int b = swz >> 6;
  int ntile = swz & 63;
  int tid = threadIdx.x;
  int lane = tid & 63;
  int wid = tid >> 6;
  int grp = wid >> 1;
  int w2 = wid & 1;
  int l31 = lane & 31;
  int h = lane >> 5;
  int nb = ntile * 64 + w2 * 32;
  char* kslot0 = lds + (size_t)wid * 16384;

  bf16x8 qf[8];
  {
    const char* qrow = (const char*)(QTb + ((size_t)b * HWN + nb + l31) * CC);
#pragma unroll
    for (int i = 0; i < 8; ++i)
      qf[i] = *(const bf16x8*)(qrow + i * 32 + h * 16);
  }

  f32x16 Of[4];
#pragma unroll
  for (int q = 0; q < 4; ++q)
#pragma unroll
    for (int r = 0; r < 16; ++r) Of[q][r] = 0.f;
  float mrun = -1e30f, lrun = 0.f;

  const char* ktB = (const char*)(KTb + (size_t)b * HWN * CC);
  const char* vtB = (const char*)Vb + ((size_t)(b * (HWN / 32) + grp * 32)) * 8192;
  int vlane = l31 * 64 + h * 16;

  auto stage = [&](int i) {
    int m0 = grp * 1024 + i * 32;
    char* buf = kslot0 + (size_t)(i & 1) * 8192;
#pragma unroll
    for (int j = 0; j < 8; ++j) {
      int row = j * 4 + (lane >> 4);
      int chk = (lane & 15) ^ (row & 15);
      g2l16(buf + j * 1024, ktB + (size_t)(m0 + row) * 256 + chk * 16);
    }
  };
  auto loadV = [&](int i, bf16x8 (&vf)[8]) {
    const char* vt = vtB + (size_t)i * 8192;
#pragma unroll
    for (int cs = 0; cs < 4; ++cs)
#pragma unroll
      for (int kk = 0; kk < 2; ++kk)
        vf[cs * 2 + kk] = *(const bf16x8*)(vt + cs * 2048 + kk * 32 + vlane);
  };

  bf16x8 vfA[8], vfB[8];

  auto step = [&](bf16x8 (&useV)[8], bf16x8 (&nextV)[8], int i,
                  bool do_stage, bool do_loadv, bool last) {
    if (last) asm volatile("s_waitcnt vmcnt(8)" ::: "memory");
    else      asm volatile("s_waitcnt vmcnt(16)" ::: "memory");
    if (do_loadv) loadV(i + 1, nextV);
    const char* kt = kslot0 + (size_t)(i & 1) * 8192;
    bf16x8 kf[8];
#pragma unroll
    for (int j = 0; j < 8; ++j) {
      int chk = (2 * j + h) ^ (l31 & 15);
      kf[j] = *(const bf16x8*)(kt + l31 * 256 + chk * 16);
    }
    asm volatile("s_waitcnt lgkmcnt(0)" ::: "memory");
    __builtin_amdgcn_sched_barrier(0);
    if (do_stage) stage(i + 2);

    f32x16 s;
#pragma unroll
    for (int r = 0; r < 16; ++r) s[r] = 0.f;
#pragma unroll
    for (int j = 0; j < 8; ++j)
      s = __builtin_amdgcn_mfma_f32_32x32x16_bf16(kf[j], qf[j], s, 0, 0, 0);
    float tm = s[0];
#pragma unroll
    for (int r = 1; r < 16; ++r) tm = fmaxf(tm, s[r]);
    tm = fmaxf(tm, __shfl_xor(tm, 32));
    if (!__all(tm <= mrun + 8.f)) {
      float mnew = fmaxf(mrun, tm);
      float alpha = exp2f(mrun - mnew);
      lrun *= alpha;
#pragma unroll
      for (int q = 0; q < 4; ++q) Of[q] *= alpha;
      mrun = mnew;
    }
    float ps = 0.f;
    bf16x8 pf0, pf1;
#pragma unroll
    for (int r = 0; r < 16; ++r) {
      float e = exp2f(s[r] - mrun);
      ps += e;
      if (r < 8) pf0[r] = (__bf16)e; else pf1[r - 8] = (__bf16)e;
    }
    ps += __shfl_xor(ps, 32);
    lrun += ps;
#pragma unroll
    for (int cs = 0; cs < 4; ++cs) {
      Of[cs] = __builtin_amdgcn_mfma_f32_32x32x16_bf16(useV[cs * 2],     pf0, Of[cs], 0, 0, 0);
      Of[cs] = __builtin_amdgcn_mfma_f32_32x32x16_bf16(useV[cs * 2 + 1], pf1, Of[cs], 0, 0, 0);
    }
  };

  stage(0);
  stage(1);
  loadV(0, vfA);
#pragma unroll 1
  for (int i = 0; i < 30; i += 2) {
    step(vfA, vfB, i,     true, true, false);
    step(vfB, vfA, i + 1, true, true, false);
  }
  step(vfA, vfB, 30, false, true,  false);
  step(vfB, vfA, 31, false, false, true);

  __syncthreads();
  float* xch = (float*)lds;
  if (grp) {
    float* rec = xch + (size_t)((grp - 1) * 128 + w2 * 64 + lane) * 68;
#pragma unroll
    for (int q = 0; q < 4; ++q)
#pragma unroll
      for (int r = 0; r < 16; ++r) rec[q * 16 + r] = Of[q][r];
    rec[64] = mrun;
    rec[65] = lrun;
  }
  __syncthreads();
  if (grp == 0) {
    const float* r1 = xch + (size_t)(0 * 128 + w2 * 64 + lane) * 68;
    const float* r2 = xch + (size_t)(1 * 128 + w2 * 64 + lane) * 68;
    const float* r3 = xch + (size_t)(2 * 128 + w2 * 64 + lane) * 68;
    float m1 = r1[64], m2 = r2[64], m3 = r3[64];
    float mm = fmaxf(fmaxf(mrun, m1), fmaxf(m2, m3));
    float a0 = exp2f(mrun - mm), a1 = exp2f(m1 - mm);
    float a2 = exp2f(m2 - mm), a3 = exp2f(m3 - mm);
    float inv = 1.f / (lrun * a0 + r1[65] * a1 + r2[65] * a2 + r3[65] * a3);
    float* outp = G2p + (size_t)b * CC * HWN + nb + l31;
#pragma unroll
    for (int q = 0; q < 4; ++q)
#pragma unroll
      for (int r = 0; r < 16; ++r) {
        int c = q * 32 + (r & 3) + 8 * (r >> 2) + 4 * h;
        float v = Of[q][r] * a0 + r1[q * 16 + r] * a1 + r2[q * 16 + r] * a2 + r3[q * 16 + r] * a3;
        outp[(size_t)c * HWN] = v * inv;
      }
  }
}

// ---------------- per-(b,c) row softmax stats of G2_pre over n ------------------
__global__ __launch_bounds__(256) void smstats_kernel(
    const float* __restrict__ G2p, float2* __restrict__ smst) {
  int row = blockIdx.x;
  const float* x = G2p + (size_t)row * HWN;
  int tid = threadIdx.x;
  float v[16];
  float mx = -1e30f;
#pragma unroll
  for (int i = 0; i < 16; ++i) { v[i] = x[tid + i * 256]; mx = fmaxf(mx, v[i]); }
#pragma unroll
  for (int off = 32; off > 0; off >>= 1) mx = fmaxf(mx, __shfl_xor(mx, off));
  __shared__ float rm[4], rs[4];
  int wid = tid >> 6;
  if ((tid & 63) == 0) rm[wid] = mx;
  __syncthreads();
  float bmax = fmaxf(fmaxf(rm[0], rm[1]), fmaxf(rm[2], rm[3]));
  float s = 0.f;
#pragma unroll
  for (int i = 0; i < 16; ++i) s += __expf(v[i] - bmax);
#pragma unroll
  for (int off = 32; off > 0; off >>= 1) s += __shfl_xor(s, off);
  if ((tid & 63) == 0) rs[wid] = s;
  __syncthreads();
  if (tid == 0) {
    float tot = rs[0] + rs[1] + rs[2] + rs[3];
    smst[row] = make_float2(bmax, 1.f / tot);
  }
}

// ---------------- gamma/beta = channel-weighted sums of softmaxed G2 ------------
__global__ __launch_bounds__(256) void gammabeta_kernel(
    const float* __restrict__ G2p, const float2* __restrict__ smst,
    const float* __restrict__ gw, const float* __restrict__ bw,
    float* __restrict__ gamma, float* __restrict__ beta) {
  int b = blockIdx.y;
  int lane = threadIdx.x & 63;
  int cg = threadIdx.x >> 6;
  int m = blockIdx.x * 64 + lane;
  const float* base = G2p + (size_t)b * CC * HWN + m;
  float ag = 0.f, ab = 0.f;
#pragma unroll 8
  for (int ci = 0; ci < 32; ++ci) {
    int c = cg * 32 + ci;
    float2 st = smst[b * CC + c];
    float val = __expf(base[(size_t)c * HWN] - st.x) * st.y;
    ag = fmaf(gw[c], val, ag);
    ab = fmaf(bw[c], val, ab);
  }
  __shared__ float sg[4][64], sb[4][64];
  sg[cg][lane] = ag;
  sb[cg][lane] = ab;
  __syncthreads();
  if (threadIdx.x < 64) {
    int t = threadIdx.x;
    gamma[b * HWN + blockIdx.x * 64 + t] = sg[0][t] + sg[1][t] + sg[2][t] + sg[3][t];
    beta[b * HWN + blockIdx.x * 64 + t]  = sb[0][t] + sb[1][t] + sb[2][t] + sb[3][t];
  }
}

// ---- out[b,o] = T[b,o]@Gam[b] + rowsum(out_w[o,:])*Beta[b] + out_b[o] ----------
__global__ __launch_bounds__(256) void final_kernel(
    const float* __restrict__ Tf, const float* __restrict__ gamma,
    const float* __restrict__ beta, const float* __restrict__ outw,
    const float* __restrict__ outb, float* __restrict__ out) {
  int o = blockIdx.x, b = blockIdx.y;
  int j = threadIdx.x & 63;
  int wid = __builtin_amdgcn_readfirstlane(threadIdx.x >> 6);
  const float* gb_ = gamma + (size_t)b * HWN;
  float gr[64];
#pragma unroll
  for (int k = 0; k < 64; ++k) gr[k] = gb_[k * 64 + j];
  float wb = 0.f;
#pragma unroll 16
  for (int c = 0; c < CC; ++c) wb += outw[o * CC + c];
  float ob = outb[o];
  const float* trow0 = Tf + ((size_t)b * CC + o) * HWN;
  const float* bbase = beta + (size_t)b * HWN;
  float* obase = out + ((size_t)b * CC + o) * HWN;
#pragma unroll 4
  for (int r = 0; r < 16; ++r) {
    int i = r * 4 + wid;
    const float* tr = trow0 + i * 64;
    float a0 = 0.f, a1 = 0.f, a2 = 0.f, a3 = 0.f;
#pragma unroll
    for (int k = 0; k < 64; k += 4) {
      a0 = fmaf(tr[k],     gr[k],     a0);
      a1 = fmaf(tr[k + 1], gr[k + 1], a1);
      a2 = fmaf(tr[k + 2], gr[k + 2], a2);
      a3 = fmaf(tr[k + 3], gr[k + 3], a3);
    }
    obase[i * 64 + j] = (a0 + a1) + (a2 + a3) + wb * bbase[i * 64 + j] + ob;
  }
}

extern "C" void kernel_launch(void* const* d_in, const int* in_sizes, int n_in,
                              void* d_out, int out_size, void* d_ws, size_t ws_size,
                              hipStream_t stream) {
  (void)in_sizes; (void)n_in; (void)out_size; (void)ws_size;
  const float* content  = (const float*)d_in[0];
  const float* guidance = (const float*)d_in[1];
  const float* g1w = (const float*)d_in[2];
  const float* g1b = (const float*)d_in[3];
  const float* fw  = (const float*)d_in[4];
  const float* fb  = (const float*)d_in[5];
  const float* hwt = (const float*)d_in[6];
  const float* hb  = (const float*)d_in[7];
  const float* gw  = (const float*)d_in[8];
  const float* bw  = (const float*)d_in[9];
  const float* outw = (const float*)d_in[10];
  const float* outb = (const float*)d_in[11];

  char* ws = (char*)d_ws;
  const size_t MB_ = 1u << 20;
  float*  Tf  = (float*)(ws + 0);            // 8 MB
  float*  G2p = (float*)(ws + 8 * MB_);      // 8 MB
  __bf16* QTb = (__bf16*)(ws + 16 * MB_);    // 4 MB
  __bf16* KTb = (__bf16*)(ws + 20 * MB_);    // 4 MB
  __bf16* Vb  = (__bf16*)(ws + 24 * MB_);    // 4 MB (tile-blocked V2)
  float2* mom  = (float2*)(ws + 28 * MB_);                  // 8 KB
  float2* smst = (float2*)(ws + 28 * MB_ + 8192);           // 4 KB
  float*  gamma = (float*)(ws + 28 * MB_ + 16384);          // 64 KB
  float*  beta  = (float*)(ws + 28 * MB_ + 16384 + 65536);  // 64 KB
  float*  W2f = (float*)(ws + 28 * MB_ + 16384 + 2 * 65536); // 64 KB
  float*  b2  = (float*)(ws + 28 * MB_ + 16384 + 3 * 65536); // 512 B
  char*   wb_ = ws + 28 * MB_ + 16384 + 3 * 65536 + 1024;
  __bf16* WK = (__bf16*)(wb_);                // 32 KB
  __bf16* WQ = (__bf16*)(wb_ + 32768);        // 32 KB
  __bf16* WT = (__bf16*)(wb_ + 65536);        // 32 KB
  __bf16* WV = (__bf16*)(wb_ + 98304);        // 128 KB
  float*  BqL  = (float*)(wb_ + 98304 + 131072);        // 512 B
  float*  hb_b = (float*)(wb_ + 98304 + 131072 + 512);  // 2 KB

  moments_kernel<<<dim3(BB * CC, 2), 256, 0, stream>>>(content, guidance, mom);
  w2prep_kernel<<<dim3(CC), 128, 0, stream>>>(outw, g1w, g1b, W2f, b2);
  wcast_kernel<<<dim3(CC, 7), 128, 0, stream>>>(
      g1w, fw, fb, hwt, hb, W2f, mom, WK, WQ, WT, WV, BqL, hb_b);
  convm_kernel<<<dim3(HWN / 128, BB, 4), 256, 0, stream>>>(
      content, guidance, mom, WK, WQ, WT, WV, g1b, b2, BqL, hb_b,
      Tf, QTb, KTb, Vb);
  attn_kernel<<<dim3(256), 512, 0, stream>>>(QTb, KTb, Vb, G2p);
  smstats_kernel<<<dim3(BB * CC), 256, 0, stream>>>(G2p, smst);
  gammabeta_kernel<<<dim3(HWN / 64, BB), 256, 0, stream>>>(G2p, smst, gw, bw, gamma, beta);
  final_kernel<<<dim3(CC, BB), 256, 0, stream>>>(Tf, gamma, beta, outw, outb, (float*)d_out);
}